// Round 3
// baseline (219.856 us; speedup 1.0000x reference)
//
#include <hip/hip_runtime.h>
#include <hip/hip_bf16.h>
#include <stdint.h>

#define Bsz 4096
#define Dn  512
#define Kn  128
#define Pn  16
#define An  32
#define TB  16

typedef __attribute__((ext_vector_type(4))) float  floatx4;
typedef __attribute__((ext_vector_type(8))) short  shortx8;

__device__ __forceinline__ unsigned short f2bf(float x) {
    union { float f; uint32_t u; } v; v.f = x;
    uint32_t u = v.u;
    uint32_t r = (u + 0x7FFFu + ((u >> 16) & 1u)) >> 16;
    return (unsigned short)r;
}

// ---------------- K1a: mu = alpha @ W (bf16 out) + ||mu_k||^2, also zeroes out ----------------
__global__ __launch_bounds__(256) void k_mu(const float* __restrict__ alpha,
                                            const float* __restrict__ W,
                                            unsigned short* __restrict__ mu_bf,
                                            float* __restrict__ munorm,
                                            float* __restrict__ out) {
    __shared__ float al[An];
    __shared__ float red[4];
    int k = blockIdx.x, t = threadIdx.x;
    if (k == 0 && t == 0) *out = 0.f;
    if (t < An) al[t] = alpha[k * An + t];
    __syncthreads();
    int d0 = t, d1 = t + 256;
    float a0 = 0.f, a1 = 0.f;
#pragma unroll
    for (int a = 0; a < An; ++a) {
        float av = al[a];
        a0 = fmaf(av, W[a * Dn + d0], a0);
        a1 = fmaf(av, W[a * Dn + d1], a1);
    }
    mu_bf[k * Dn + d0] = f2bf(a0);  mu_bf[k * Dn + d1] = f2bf(a1);
    float nrm = a0 * a0 + a1 * a1;
#pragma unroll
    for (int msk = 1; msk < 64; msk <<= 1) nrm += __shfl_xor(nrm, msk);
    if ((t & 63) == 0) red[t >> 6] = nrm;
    __syncthreads();
    if (t == 0) munorm[k] = red[0] + red[1] + red[2] + red[3];
}

// ---------------- K1b: Gram G = mu @ mu^T via MFMA (coalesced) ----------------
__global__ __launch_bounds__(512) void k_gram(const unsigned short* __restrict__ mu_bf,
                                              unsigned short* __restrict__ G_bf) {
    __shared__ short at[TB][520];
    const int tid = threadIdx.x;
    const int lane = tid & 63;
    const int wv = tid >> 6;
    const int m = lane & 15;
    const int q = lane >> 4;
    const int i0 = blockIdx.x * TB;

    const int r = tid >> 5, c0 = (tid & 31) * 16;
    const int4* src = (const int4*)(mu_bf + (size_t)(i0 + r) * Dn + c0);
    *(int4*)&at[r][c0]     = src[0];
    *(int4*)&at[r][c0 + 8] = src[1];

    const int kcol = wv * 16 + m;
    shortx8 bfrag[16];
    const unsigned short* mb = mu_bf + (size_t)kcol * Dn + q * 8;
#pragma unroll
    for (int dc = 0; dc < 16; ++dc) bfrag[dc] = *(const shortx8*)(mb + dc * 32);
    __syncthreads();

    floatx4 acc = {0.f, 0.f, 0.f, 0.f};
#pragma unroll
    for (int dc = 0; dc < 16; ++dc) {
        shortx8 a = *(const shortx8*)&at[m][dc * 32 + q * 8];
        acc = __builtin_amdgcn_mfma_f32_16x16x32_bf16(a, bfrag[dc], acc, 0, 0, 0);
    }
#pragma unroll
    for (int i = 0; i < 4; ++i)
        G_bf[(size_t)(i0 + q * 4 + i) * Kn + kcol] = f2bf(acc[i]);
}

// ---------------- K3: flipped-operand streaming probe contraction ----------------
// MFMA as D[k][b] (A=mu rows=k, B=v cols=b): each lane owns ONE b-row with 4
// k-partials and 4 register weights -> per-probe reduction is 2 shuffles for
// the scalar s2 only; sum_k w*T^2 accumulates per-lane across all probes and
// is reduced once at the end. Removes the 32-bperm/probe LDS-pipe serial cost.
__global__ __launch_bounds__(512, 4) void k_main(
    const float* __restrict__ thetas,
    const int* __restrict__ v_int,
    const unsigned short* __restrict__ mu_bf,
    const float* __restrict__ munorm,
    const unsigned short* __restrict__ G_bf,
    const int* __restrict__ Np,
    float* __restrict__ out)
{
    __shared__ short vt[2][TB][520];   // staged tile (theta, then v probes)
    __shared__ float S_l[Kn][21];      // S scores, [k][b], pad 21 (odd stride)
    __shared__ float w_l[TB][132];     // softmax weights fp32, [b][k]
    __shared__ short wbf[TB][136];     // softmax weights bf16, [b][k]
    __shared__ float ps2[2][8][TB];    // per-wave s2 partials (double-buffered)
    __shared__ float ps1[8][TB];       // per-wave final S1 partials
    __shared__ float thn[TB];
    __shared__ float SwS[TB];

    const int tid = threadIdx.x;
    const int lane = tid & 63;
    const int wv = tid >> 6;           // wave 0..7 -> k-range [wv*16, wv*16+16)
    const int m = lane & 15;           // = b-column in flipped D layout
    const int q = lane >> 4;

    const int tileb = blockIdx.x >> 1;
    const int phalf = blockIdx.x & 1;
    const int b0 = tileb * TB;
    const int p0 = phalf * 8;

    const float Nf = (float)(*Np);
    const float temper = Nf / (Nf + 1.0f);

    // mu A-fragments: lane m holds row kcol=wv*16+m, d = dc*32 + q*8 + j
    const int kcol = wv * 16 + m;
    shortx8 mufrag[16];
    {
        const unsigned short* mb = mu_bf + (size_t)kcol * Dn + q * 8;
#pragma unroll
        for (int dc = 0; dc < 16; ++dc)
            mufrag[dc] = *(const shortx8*)(mb + dc * 32);
    }

    const int r = tid >> 5;
    const int c0 = (tid & 31) * 16;
    const size_t PB = (size_t)Bsz * Dn;
    const int* vrow = v_int + (size_t)(b0 + r) * Dn + c0;

    int4 buf[4];
    {   // prefetch probe p0
        const int4* g = (const int4*)(vrow + (size_t)p0 * PB);
#pragma unroll
        for (int j = 0; j < 4; ++j) buf[j] = g[j];
    }
    {   // stage theta -> vt[0] (bf16) + ||theta||^2
        const float4* tg = (const float4*)(thetas + (size_t)(b0 + r) * Dn + c0);
        float tn = 0.f;
#pragma unroll
        for (int j = 0; j < 4; ++j) {
            float4 f = tg[j];
            tn += f.x * f.x + f.y * f.y + f.z * f.z + f.w * f.w;
            short4 h;
            h.x = (short)f2bf(f.x); h.y = (short)f2bf(f.y);
            h.z = (short)f2bf(f.z); h.w = (short)f2bf(f.w);
            *(short4*)&vt[0][r][c0 + j * 4] = h;
        }
#pragma unroll
        for (int msk = 1; msk < 32; msk <<= 1) tn += __shfl_xor(tn, msk);
        if ((tid & 31) == 0) thn[r] = tn;
    }
    __syncthreads();

    // ---- S pass: D[k][b] = mu @ theta^T ----
    {
        floatx4 acc = {0.f, 0.f, 0.f, 0.f};
#pragma unroll
        for (int dc = 0; dc < 16; ++dc) {
            shortx8 bfr = *(const shortx8*)&vt[0][m][dc * 32 + q * 8];
            acc = __builtin_amdgcn_mfma_f32_16x16x32_bf16(mufrag[dc], bfr, acc, 0, 0, 0);
        }
#pragma unroll
        for (int i = 0; i < 4; ++i) S_l[wv * 16 + q * 4 + i][m] = acc[i];
    }
    __syncthreads();

    // ---- softmax over k (32 threads per b-row) ----
    {
        const int b = tid >> 5, s = tid & 31;
        float l[4];
        float mx = -3.4e38f;
        float tnb = thn[b];
#pragma unroll
        for (int j = 0; j < 4; ++j) {
            int k = s + 32 * j;
            l[j] = -0.5f * (tnb - 2.f * S_l[k][b] + munorm[k]);
            mx = fmaxf(mx, l[j]);
        }
#pragma unroll
        for (int msk = 1; msk < 32; msk <<= 1) mx = fmaxf(mx, __shfl_xor(mx, msk));
        float se = 0.f, ses = 0.f;
        float e[4];
#pragma unroll
        for (int j = 0; j < 4; ++j) {
            int k = s + 32 * j;
            e[j] = __expf(l[j] - mx);
            se += e[j];
            ses += e[j] * S_l[k][b];
        }
#pragma unroll
        for (int msk = 1; msk < 32; msk <<= 1) { se += __shfl_xor(se, msk); ses += __shfl_xor(ses, msk); }
        float inv = 1.f / se;
#pragma unroll
        for (int j = 0; j < 4; ++j) {
            int k = s + 32 * j;
            float wvv = e[j] * inv;
            w_l[b][k] = wvv;
            wbf[b][k] = (short)f2bf(wvv);
        }
        if (s == 0) SwS[b] = ses * inv;
    }
    __syncthreads();

    // per-lane weights: w[b=m][k = kcol quad] — constant across probes
    float wreg[4];
#pragma unroll
    for (int i = 0; i < 4; ++i) wreg[i] = w_l[m][wv * 16 + q * 4 + i];

    // ---- wGw: D[k][b] = G @ w^T, dotted with wreg ----
    {
        shortx8 gfrag[4];
        const unsigned short* gb = G_bf + (size_t)kcol * Kn + q * 8;
#pragma unroll
        for (int kc = 0; kc < 4; ++kc) gfrag[kc] = *(const shortx8*)(gb + kc * 32);
        floatx4 acc = {0.f, 0.f, 0.f, 0.f};
#pragma unroll
        for (int kc = 0; kc < 4; ++kc) {
            shortx8 bfr = *(const shortx8*)&wbf[m][kc * 32 + q * 8];
            acc = __builtin_amdgcn_mfma_f32_16x16x32_bf16(gfrag[kc], bfr, acc, 0, 0, 0);
        }
        float sg = wreg[0] * acc[0] + wreg[1] * acc[1] + wreg[2] * acc[2] + wreg[3] * acc[3];
        sg += __shfl_xor(sg, 16);
        sg += __shfl_xor(sg, 32);
        if (q == 0) ps2[0][wv][m] = sg;
    }
    __syncthreads();

    float lossA = 0.f;
    if (tid < TB) {
        float wGw = 0.f;
#pragma unroll
        for (int w8 = 0; w8 < 8; ++w8) wGw += ps2[0][w8][tid];
        if (phalf == 0)
            lossA = 0.5f * temper * temper * (wGw - 2.f * SwS[tid] + thn[tid])
                    - temper * (float)Dn;
    }

    // ---- probe loop: 1 barrier per probe; s2 per-probe, S1 deferred ----
    float S1s = 0.f;    // per-lane sum_p sum_i wreg*T^2
    float sqacc = 0.f;  // (tid<16 only) sum_p s2_p^2
#pragma unroll
    for (int p = 0; p < 8; ++p) {
        // convert buf (0/1 int) -> bf16 ±1 into vt[p&1]
#pragma unroll
        for (int j = 0; j < 4; ++j) {
            int4 w4 = buf[j];
            short4 h;
            h.x = (short)((w4.x << 15) ^ 0xBF80);
            h.y = (short)((w4.y << 15) ^ 0xBF80);
            h.z = (short)((w4.z << 15) ^ 0xBF80);
            h.w = (short)((w4.w << 15) ^ 0xBF80);
            *(short4*)&vt[p & 1][r][c0 + j * 4] = h;
        }
        __syncthreads();
        if (p < 7) {   // prefetch after barrier: lands during MFMA phase
            const int4* g = (const int4*)(vrow + (size_t)(p0 + p + 1) * PB);
#pragma unroll
            for (int j = 0; j < 4; ++j) buf[j] = g[j];
        }
        if (p > 0 && tid < TB) {   // deferred s2 combine for probe p-1
            float s2c = 0.f;
#pragma unroll
            for (int w8 = 0; w8 < 8; ++w8) s2c += ps2[(p - 1) & 1][w8][tid];
            sqacc += s2c * s2c;
        }
        floatx4 acc = {0.f, 0.f, 0.f, 0.f};
#pragma unroll
        for (int dc = 0; dc < 16; ++dc) {
            shortx8 bfr = *(const shortx8*)&vt[p & 1][m][dc * 32 + q * 8];
            acc = __builtin_amdgcn_mfma_f32_16x16x32_bf16(mufrag[dc], bfr, acc, 0, 0, 0);
        }
        float s2p = 0.f;
#pragma unroll
        for (int i = 0; i < 4; ++i) {
            float T = acc[i];
            float wT = wreg[i] * T;
            s2p += wT;
            S1s = fmaf(wT, T, S1s);
        }
        s2p += __shfl_xor(s2p, 16);
        s2p += __shfl_xor(s2p, 32);
        if (q == 0) ps2[p & 1][wv][m] = s2p;
        // no trailing barrier: next iteration's barrier orders reuse
    }

    // final per-lane S1 reduce over q, then cross-wave combine
    S1s += __shfl_xor(S1s, 16);
    S1s += __shfl_xor(S1s, 32);
    if (q == 0) ps1[wv][m] = S1s;
    __syncthreads();

    if (tid < TB) {
        float s2c = 0.f, S1tot = 0.f;
#pragma unroll
        for (int w8 = 0; w8 < 8; ++w8) {
            s2c += ps2[1][w8][tid];
            S1tot += ps1[w8][tid];
        }
        sqacc += s2c * s2c;
        float res = temper * (S1tot - sqacc) * (1.0f / (float)Pn) + lossA;
#pragma unroll
        for (int msk = 1; msk < 16; msk <<= 1) res += __shfl_xor(res, msk);
        if (tid == 0) atomicAdd(out, res * (1.0f / (float)Bsz));
    }
}

extern "C" void kernel_launch(void* const* d_in, const int* in_sizes, int n_in,
                              void* d_out, int out_size, void* d_ws, size_t ws_size,
                              hipStream_t stream) {
    const float* thetas = (const float*)d_in[0];
    const float* alpha  = (const float*)d_in[1];
    const float* W      = (const float*)d_in[2];
    const int*   v_int  = (const int*)d_in[3];
    const int*   Np     = (const int*)d_in[4];

    char* ws = (char*)d_ws;
    unsigned short* mu_bf  = (unsigned short*)ws;                    // 128 KB
    float*          munorm = (float*)(ws + 131072);                  // 512 B
    unsigned short* G_bf   = (unsigned short*)(ws + 131072 + 1024);  // 32 KB

    float* out = (float*)d_out;
    k_mu  <<<dim3(Kn), dim3(256), 0, stream>>>(alpha, W, mu_bf, munorm, out);
    k_gram<<<dim3(8),  dim3(512), 0, stream>>>(mu_bf, G_bf);
    k_main<<<dim3(512), dim3(512), 0, stream>>>(thetas, v_int, mu_bf, munorm, G_bf, Np, out);
}

// Round 4
// 219.090 us; speedup vs baseline: 1.0035x; 1.0035x over previous
//
#include <hip/hip_runtime.h>
#include <hip/hip_bf16.h>
#include <stdint.h>

#define Bsz 4096
#define Dn  512
#define Kn  128
#define Pn  16
#define An  32
#define TB  16

typedef __attribute__((ext_vector_type(4))) float  floatx4;
typedef __attribute__((ext_vector_type(8))) short  shortx8;

__device__ __forceinline__ unsigned short f2bf(float x) {
    union { float f; uint32_t u; } v; v.f = x;
    uint32_t u = v.u;
    uint32_t r = (u + 0x7FFFu + ((u >> 16) & 1u)) >> 16;
    return (unsigned short)r;
}

// ---------------- K1a: mu = alpha @ W (bf16 out) + ||mu_k||^2, also zeroes out ----------------
__global__ __launch_bounds__(256) void k_mu(const float* __restrict__ alpha,
                                            const float* __restrict__ W,
                                            unsigned short* __restrict__ mu_bf,
                                            float* __restrict__ munorm,
                                            float* __restrict__ out) {
    __shared__ float al[An];
    __shared__ float red[4];
    int k = blockIdx.x, t = threadIdx.x;
    if (k == 0 && t == 0) *out = 0.f;
    if (t < An) al[t] = alpha[k * An + t];
    __syncthreads();
    int d0 = t, d1 = t + 256;
    float a0 = 0.f, a1 = 0.f;
#pragma unroll
    for (int a = 0; a < An; ++a) {
        float av = al[a];
        a0 = fmaf(av, W[a * Dn + d0], a0);
        a1 = fmaf(av, W[a * Dn + d1], a1);
    }
    mu_bf[k * Dn + d0] = f2bf(a0);  mu_bf[k * Dn + d1] = f2bf(a1);
    float nrm = a0 * a0 + a1 * a1;
#pragma unroll
    for (int msk = 1; msk < 64; msk <<= 1) nrm += __shfl_xor(nrm, msk);
    if ((t & 63) == 0) red[t >> 6] = nrm;
    __syncthreads();
    if (t == 0) munorm[k] = red[0] + red[1] + red[2] + red[3];
}

// ---------------- K1b: Gram G = mu @ mu^T via MFMA (coalesced) ----------------
__global__ __launch_bounds__(512) void k_gram(const unsigned short* __restrict__ mu_bf,
                                              unsigned short* __restrict__ G_bf) {
    __shared__ short at[TB][520];
    const int tid = threadIdx.x;
    const int lane = tid & 63;
    const int wv = tid >> 6;
    const int m = lane & 15;
    const int q = lane >> 4;
    const int i0 = blockIdx.x * TB;

    const int r = tid >> 5, c0 = (tid & 31) * 16;
    const int4* src = (const int4*)(mu_bf + (size_t)(i0 + r) * Dn + c0);
    *(int4*)&at[r][c0]     = src[0];
    *(int4*)&at[r][c0 + 8] = src[1];

    const int kcol = wv * 16 + m;
    shortx8 bfrag[16];
    const unsigned short* mb = mu_bf + (size_t)kcol * Dn + q * 8;
#pragma unroll
    for (int dc = 0; dc < 16; ++dc) bfrag[dc] = *(const shortx8*)(mb + dc * 32);
    __syncthreads();

    floatx4 acc = {0.f, 0.f, 0.f, 0.f};
#pragma unroll
    for (int dc = 0; dc < 16; ++dc) {
        shortx8 a = *(const shortx8*)&at[m][dc * 32 + q * 8];
        acc = __builtin_amdgcn_mfma_f32_16x16x32_bf16(a, bfrag[dc], acc, 0, 0, 0);
    }
#pragma unroll
    for (int i = 0; i < 4; ++i)
        G_bf[(size_t)(i0 + q * 4 + i) * Kn + kcol] = f2bf(acc[i]);
}

// ---------------- K3: flipped-operand streaming probe contraction ----------------
// D[k][b] layout (A=mu, B=v): lane owns one b with 4 k-partials + 4 register
// weights; per-probe reduction = 2 shuffles (s2 only), S1 deferred to the end.
// v staging: converted ±1 bf16 packed in-register -> 2x ds_write_b128/thread
// (chunk starts were {0,8,16,24} 8-deep with b64 -> halved bank pressure).
__global__ __launch_bounds__(512, 4) void k_main(
    const float* __restrict__ thetas,
    const int* __restrict__ v_int,
    const unsigned short* __restrict__ mu_bf,
    const float* __restrict__ munorm,
    const unsigned short* __restrict__ G_bf,
    const int* __restrict__ Np,
    float* __restrict__ out)
{
    __shared__ short vt[2][TB][520];
    __shared__ float S_l[Kn][21];
    __shared__ float w_l[TB][132];
    __shared__ short wbf[TB][136];
    __shared__ float ps2[2][8][TB];
    __shared__ float ps1[8][TB];
    __shared__ float thn[TB];
    __shared__ float SwS[TB];

    const int tid = threadIdx.x;
    const int lane = tid & 63;
    const int wv = tid >> 6;
    const int m = lane & 15;
    const int q = lane >> 4;

    const int tileb = blockIdx.x >> 1;
    const int phalf = blockIdx.x & 1;
    const int b0 = tileb * TB;
    const int p0 = phalf * 8;

    const float Nf = (float)(*Np);
    const float temper = Nf / (Nf + 1.0f);

    const int kcol = wv * 16 + m;
    shortx8 mufrag[16];
    {
        const unsigned short* mb = mu_bf + (size_t)kcol * Dn + q * 8;
#pragma unroll
        for (int dc = 0; dc < 16; ++dc)
            mufrag[dc] = *(const shortx8*)(mb + dc * 32);
    }

    const int r = tid >> 5;
    const int c0 = (tid & 31) * 16;
    const size_t PB = (size_t)Bsz * Dn;
    const int* vrow = v_int + (size_t)(b0 + r) * Dn + c0;

    int4 buf[4];
    {
        const int4* g = (const int4*)(vrow + (size_t)p0 * PB);
#pragma unroll
        for (int j = 0; j < 4; ++j) buf[j] = g[j];
    }
    {   // stage theta -> vt[0] (bf16) + ||theta||^2
        const float4* tg = (const float4*)(thetas + (size_t)(b0 + r) * Dn + c0);
        float tn = 0.f;
#pragma unroll
        for (int j = 0; j < 2; ++j) {
            float4 f0 = tg[2 * j], f1 = tg[2 * j + 1];
            tn += f0.x * f0.x + f0.y * f0.y + f0.z * f0.z + f0.w * f0.w;
            tn += f1.x * f1.x + f1.y * f1.y + f1.z * f1.z + f1.w * f1.w;
            int4 pk;
            pk.x = (int)f2bf(f0.x) | ((int)f2bf(f0.y) << 16);
            pk.y = (int)f2bf(f0.z) | ((int)f2bf(f0.w) << 16);
            pk.z = (int)f2bf(f1.x) | ((int)f2bf(f1.y) << 16);
            pk.w = (int)f2bf(f1.z) | ((int)f2bf(f1.w) << 16);
            *(int4*)&vt[0][r][c0 + j * 8] = pk;
        }
#pragma unroll
        for (int msk = 1; msk < 32; msk <<= 1) tn += __shfl_xor(tn, msk);
        if ((tid & 31) == 0) thn[r] = tn;
    }
    __syncthreads();

    // ---- S pass: D[k][b] = mu @ theta^T ----
    {
        floatx4 acc = {0.f, 0.f, 0.f, 0.f};
#pragma unroll
        for (int dc = 0; dc < 16; ++dc) {
            shortx8 bfr = *(const shortx8*)&vt[0][m][dc * 32 + q * 8];
            acc = __builtin_amdgcn_mfma_f32_16x16x32_bf16(mufrag[dc], bfr, acc, 0, 0, 0);
        }
#pragma unroll
        for (int i = 0; i < 4; ++i) S_l[wv * 16 + q * 4 + i][m] = acc[i];
    }
    __syncthreads();

    // ---- softmax over k (32 threads per b-row) ----
    {
        const int b = tid >> 5, s = tid & 31;
        float l[4];
        float mx = -3.4e38f;
        float tnb = thn[b];
#pragma unroll
        for (int j = 0; j < 4; ++j) {
            int k = s + 32 * j;
            l[j] = -0.5f * (tnb - 2.f * S_l[k][b] + munorm[k]);
            mx = fmaxf(mx, l[j]);
        }
#pragma unroll
        for (int msk = 1; msk < 32; msk <<= 1) mx = fmaxf(mx, __shfl_xor(mx, msk));
        float se = 0.f, ses = 0.f;
        float e[4];
#pragma unroll
        for (int j = 0; j < 4; ++j) {
            int k = s + 32 * j;
            e[j] = __expf(l[j] - mx);
            se += e[j];
            ses += e[j] * S_l[k][b];
        }
#pragma unroll
        for (int msk = 1; msk < 32; msk <<= 1) { se += __shfl_xor(se, msk); ses += __shfl_xor(ses, msk); }
        float inv = 1.f / se;
#pragma unroll
        for (int j = 0; j < 4; ++j) {
            int k = s + 32 * j;
            float wvv = e[j] * inv;
            w_l[b][k] = wvv;
            wbf[b][k] = (short)f2bf(wvv);
        }
        if (s == 0) SwS[b] = ses * inv;
    }
    __syncthreads();

    float wreg[4];
#pragma unroll
    for (int i = 0; i < 4; ++i) wreg[i] = w_l[m][wv * 16 + q * 4 + i];

    // ---- wGw: D[k][b] = G @ w^T, dotted with wreg ----
    {
        shortx8 gfrag[4];
        const unsigned short* gb = G_bf + (size_t)kcol * Kn + q * 8;
#pragma unroll
        for (int kc = 0; kc < 4; ++kc) gfrag[kc] = *(const shortx8*)(gb + kc * 32);
        floatx4 acc = {0.f, 0.f, 0.f, 0.f};
#pragma unroll
        for (int kc = 0; kc < 4; ++kc) {
            shortx8 bfr = *(const shortx8*)&wbf[m][kc * 32 + q * 8];
            acc = __builtin_amdgcn_mfma_f32_16x16x32_bf16(gfrag[kc], bfr, acc, 0, 0, 0);
        }
        float sg = wreg[0] * acc[0] + wreg[1] * acc[1] + wreg[2] * acc[2] + wreg[3] * acc[3];
        sg += __shfl_xor(sg, 16);
        sg += __shfl_xor(sg, 32);
        if (q == 0) ps2[0][wv][m] = sg;
    }
    __syncthreads();

    float lossA = 0.f;
    if (tid < TB) {
        float wGw = 0.f;
#pragma unroll
        for (int w8 = 0; w8 < 8; ++w8) wGw += ps2[0][w8][tid];
        if (phalf == 0)
            lossA = 0.5f * temper * temper * (wGw - 2.f * SwS[tid] + thn[tid])
                    - temper * (float)Dn;
    }

    // ---- probe loop: 1 barrier per probe ----
    float S1s = 0.f;
    float sqacc = 0.f;
#pragma unroll
    for (int p = 0; p < 8; ++p) {
        // convert buf (0/1 int) -> packed bf16 +/-1, 2x b128 stores
#pragma unroll
        for (int j = 0; j < 2; ++j) {
            int4 A = buf[2 * j], Bv = buf[2 * j + 1];
            int4 pk;
            pk.x = (int)(0xBF80BF80u ^ (A.x  << 15) ^ (A.y  << 31));
            pk.y = (int)(0xBF80BF80u ^ (A.z  << 15) ^ (A.w  << 31));
            pk.z = (int)(0xBF80BF80u ^ (Bv.x << 15) ^ (Bv.y << 31));
            pk.w = (int)(0xBF80BF80u ^ (Bv.z << 15) ^ (Bv.w << 31));
            *(int4*)&vt[p & 1][r][c0 + j * 8] = pk;
        }
        __syncthreads();
        if (p < 7) {   // prefetch after barrier: never drained by syncthreads
            const int4* g = (const int4*)(vrow + (size_t)(p0 + p + 1) * PB);
#pragma unroll
            for (int j = 0; j < 4; ++j) buf[j] = g[j];
        }
        if (p > 0 && tid < TB) {   // deferred s2 combine for probe p-1
            float s2c = 0.f;
#pragma unroll
            for (int w8 = 0; w8 < 8; ++w8) s2c += ps2[(p - 1) & 1][w8][tid];
            sqacc += s2c * s2c;
        }
        floatx4 acc = {0.f, 0.f, 0.f, 0.f};
#pragma unroll
        for (int dc = 0; dc < 16; ++dc) {
            shortx8 bfr = *(const shortx8*)&vt[p & 1][m][dc * 32 + q * 8];
            acc = __builtin_amdgcn_mfma_f32_16x16x32_bf16(mufrag[dc], bfr, acc, 0, 0, 0);
        }
        float s2p = 0.f;
#pragma unroll
        for (int i = 0; i < 4; ++i) {
            float T = acc[i];
            float wT = wreg[i] * T;
            s2p += wT;
            S1s = fmaf(wT, T, S1s);
        }
        s2p += __shfl_xor(s2p, 16);
        s2p += __shfl_xor(s2p, 32);
        if (q == 0) ps2[p & 1][wv][m] = s2p;
    }

    S1s += __shfl_xor(S1s, 16);
    S1s += __shfl_xor(S1s, 32);
    if (q == 0) ps1[wv][m] = S1s;
    __syncthreads();

    if (tid < TB) {
        float s2c = 0.f, S1tot = 0.f;
#pragma unroll
        for (int w8 = 0; w8 < 8; ++w8) {
            s2c += ps2[1][w8][tid];
            S1tot += ps1[w8][tid];
        }
        sqacc += s2c * s2c;
        float res = temper * (S1tot - sqacc) * (1.0f / (float)Pn) + lossA;
#pragma unroll
        for (int msk = 1; msk < 16; msk <<= 1) res += __shfl_xor(res, msk);
        if (tid == 0) atomicAdd(out, res * (1.0f / (float)Bsz));
    }
}

extern "C" void kernel_launch(void* const* d_in, const int* in_sizes, int n_in,
                              void* d_out, int out_size, void* d_ws, size_t ws_size,
                              hipStream_t stream) {
    const float* thetas = (const float*)d_in[0];
    const float* alpha  = (const float*)d_in[1];
    const float* W      = (const float*)d_in[2];
    const int*   v_int  = (const int*)d_in[3];
    const int*   Np     = (const int*)d_in[4];

    char* ws = (char*)d_ws;
    unsigned short* mu_bf  = (unsigned short*)ws;                    // 128 KB
    float*          munorm = (float*)(ws + 131072);                  // 512 B
    unsigned short* G_bf   = (unsigned short*)(ws + 131072 + 1024);  // 32 KB

    float* out = (float*)d_out;
    k_mu  <<<dim3(Kn), dim3(256), 0, stream>>>(alpha, W, mu_bf, munorm, out);
    k_gram<<<dim3(8),  dim3(512), 0, stream>>>(mu_bf, G_bf);
    k_main<<<dim3(512), dim3(512), 0, stream>>>(thetas, v_int, mu_bf, munorm, G_bf, Np, out);
}